// Round 1
// baseline (3676.973 us; speedup 1.0000x reference)
//
#include <hip/hip_runtime.h>
#include <hip/hip_bf16.h>

// RPN proposal head for MI355X.
// Stages: conv3x3(f64 acc) -> 1x1 heads + sigmoid + decode (f64) -> hist ->
// radix-bucket threshold -> compact -> bitonic sort top-6000 -> NMS mask ->
// serial-scan NMS + top-300 select -> write rois/scores; feature d2d copy.
//
// f64 accumulation everywhere on the score path: output ordering (which box
// lands in which of the 300 output rows) is decided by score comparisons with
// gaps ~1e-6; fp32 accumulation drift (~2e-6 over K=4608) risks row swaps that
// blow the 40.96 absmax threshold. fp32*fp32 is exact in double FMA.

#define HH 128
#define WW 128
#define HW 16384
#define CC 512
#define NANCH 9
#define NTOT 147456          // HW * 9
#define PRE_TOPN 6000
#define POST_TOPN 300
#define NMS_WORDS 94         // ceil(6000/64)
#define CAND_CAP 16384

typedef unsigned int u32;
typedef unsigned long long u64;

// Base anchors from _base_anchors(16): scales {8,16,32} x ratios {.5,1,2},
// numpy banker's rounding applied. Order: (r.5,s8)(r.5,s16)(r.5,s32)(r1,..)(r2,..)
__constant__ float c_anch[9][4] = {
  { -84.f,  -40.f,  99.f,  55.f},
  {-176.f,  -88.f, 191.f, 103.f},
  {-360.f, -184.f, 375.f, 199.f},
  { -56.f,  -56.f,  71.f,  71.f},
  {-120.f, -120.f, 135.f, 135.f},
  {-248.f, -248.f, 263.f, 263.f},
  { -36.f,  -80.f,  51.f,  95.f},
  { -80.f, -168.f,  95.f, 183.f},
  {-168.f, -344.f, 183.f, 351.f}
};

// ---------------------------------------------------------------- conv 3x3
// block: 64 oc x (2 rows x 128 cols) px, 256 threads, K chunks of 8 ic.
// grid: 8 oc-tiles x 64 row-pairs = 512 blocks.
__global__ __launch_bounds__(256, 2)
void conv3x3(const float* __restrict__ feat, const float* __restrict__ wconv,
             const float* __restrict__ bias, float* __restrict__ out)
{
  __shared__ float sA[8][4][136];   // [ic][row-1..row+2][4 + col + pad], 17.4KB
  __shared__ float sW[72][64];      // [(ic*9 + ky*3 + kx)][oc], 18.4KB
  const int tid  = threadIdx.x;
  const int oc0  = (blockIdx.x & 7) << 6;
  const int r0   = (blockIdx.x >> 3) << 1;
  const int px_g = tid & 31;          // 32 col-octet groups
  const int oc_g = tid >> 5;          // 8 oc groups of 8
  const int prow = px_g >> 4;         // 0..1
  const int pcol = (px_g & 15) << 3;  // 0,8,...,120

  // zero the two halo columns (LDS col 3 and 132) once; staging never writes them
  if (tid < 64) {
    int ic = tid >> 3, rr = (tid >> 1) & 3, col = (tid & 1) ? 132 : 3;
    sA[ic][rr][col] = 0.f;
  }

  double acc[8][8];
  #pragma unroll
  for (int o = 0; o < 8; ++o) {
    double bv = (double)bias[oc0 + oc_g * 8 + o];
    #pragma unroll
    for (int j = 0; j < 8; ++j) acc[o][j] = bv;
  }

  for (int ic0 = 0; ic0 < CC; ic0 += 8) {
    __syncthreads();
    // stage input: 8 ic x 4 rows x 128 cols, float4, coalesced
    #pragma unroll
    for (int k = 0; k < 4; ++k) {
      int s  = tid + 256 * k;          // 1024 float4 slots
      int icr = s >> 5;                // 0..31 (ic,row)
      int ic = icr >> 2, rr = icr & 3;
      int c4 = (s & 31) << 2;
      int grow = r0 - 1 + rr;
      float4 v = make_float4(0.f, 0.f, 0.f, 0.f);
      if (grow >= 0 && grow < HH)
        v = *reinterpret_cast<const float4*>(&feat[(ic0 + ic) * HW + grow * WW + c4]);
      *reinterpret_cast<float4*>(&sA[ic][rr][4 + c4]) = v;
    }
    // stage weights transposed: sW[tap][oc]
    {
      int oc = tid & 63, part = tid >> 6;
      const float* wp = &wconv[(size_t)((oc0 + oc) * CC + ic0) * 9 + part * 18];
      #pragma unroll
      for (int k = 0; k < 18; ++k) sW[part * 18 + k][oc] = wp[k];
    }
    __syncthreads();

    for (int ic = 0; ic < 8; ++ic) {
      #pragma unroll
      for (int ky = 0; ky < 3; ++ky) {
        double a[10];
        #pragma unroll
        for (int j = 0; j < 10; ++j)
          a[j] = (double)sA[ic][prow + ky][3 + pcol + j];  // col pcol-1+j
        #pragma unroll
        for (int kx = 0; kx < 3; ++kx) {
          double wv[8];
          #pragma unroll
          for (int o = 0; o < 8; ++o)
            wv[o] = (double)sW[ic * 9 + ky * 3 + kx][oc_g * 8 + o];
          #pragma unroll
          for (int o = 0; o < 8; ++o)
            #pragma unroll
            for (int j = 0; j < 8; ++j)
              acc[o][j] = fma(a[kx + j], wv[o], acc[o][j]);
        }
      }
    }
  }

  const int orow = r0 + prow;
  #pragma unroll
  for (int o = 0; o < 8; ++o) {
    float* op = &out[(size_t)(oc0 + oc_g * 8 + o) * HW + orow * WW + pcol];
    float4 v0, v1;
    v0.x = (float)acc[o][0]; v0.y = (float)acc[o][1];
    v0.z = (float)acc[o][2]; v0.w = (float)acc[o][3];
    v1.x = (float)acc[o][4]; v1.y = (float)acc[o][5];
    v1.z = (float)acc[o][6]; v1.w = (float)acc[o][7];
    *reinterpret_cast<float4*>(op)     = v0;
    *reinterpret_cast<float4*>(op + 4) = v1;
  }
}

// ------------------------------------------- 1x1 heads + sigmoid + decode
// block: 64 px, 54 outputs (18 cls + 36 bbox), f64 acc; fused score-histogram.
__global__ __launch_bounds__(256, 2)
void conv1x1_decode(const float* __restrict__ rfeat, const float* __restrict__ wsc,
                    const float* __restrict__ bsc, const float* __restrict__ wbb,
                    const float* __restrict__ bbb, const int* __restrict__ im_info,
                    float* __restrict__ scores, double4* __restrict__ props,
                    u32* __restrict__ hist)
{
  __shared__ float  sA[32][64];     // 8KB
  __shared__ float  sW[32][56];     // 7KB (cols 54,55 zero pad)
  __shared__ double sOut[64][56];   // 28KB
  const int tid  = threadIdx.x;
  const int px0  = blockIdx.x * 64;
  const int q    = tid >> 6;        // 0..3 -> 14 outputs each
  const int px_l = tid & 63;
  const int o0   = q * 14;

  double acc[14];
  #pragma unroll
  for (int o = 0; o < 14; ++o) {
    int oo = o0 + o;
    float b = 0.f;
    if (oo < 18) b = bsc[oo];
    else if (oo < 54) b = bbb[oo - 18];
    acc[o] = (double)b;
  }

  for (int ic0 = 0; ic0 < CC; ic0 += 32) {
    __syncthreads();
    #pragma unroll
    for (int k = 0; k < 2; ++k) {
      int s  = tid + 256 * k;       // 512 float4 slots
      int ic = s >> 4;
      int c4 = (s & 15) << 2;
      *reinterpret_cast<float4*>(&sA[ic][c4]) =
        *reinterpret_cast<const float4*>(&rfeat[(ic0 + ic) * HW + px0 + c4]);
    }
    for (int idx = tid; idx < 32 * 56; idx += 256) {
      int ic = idx / 56, o = idx % 56;
      float v = 0.f;
      if (o < 18) v = wsc[o * CC + ic0 + ic];
      else if (o < 54) v = wbb[(o - 18) * CC + ic0 + ic];
      sW[ic][o] = v;
    }
    __syncthreads();
    for (int ic = 0; ic < 32; ++ic) {
      double a = (double)sA[ic][px_l];
      #pragma unroll
      for (int o = 0; o < 14; ++o)
        acc[o] = fma(a, (double)sW[ic][o0 + o], acc[o]);
    }
  }
  #pragma unroll
  for (int o = 0; o < 14; ++o) sOut[px_l][o0 + o] = acc[o];
  __syncthreads();

  const double im_h = (double)im_info[0];
  const double im_w = (double)im_info[1];
  const double BCLIP = 4.1351665567423557;   // log(1000/16)
  for (int t = tid; t < 64 * NANCH; t += 256) {
    int pl = t / 9, a = t % 9;
    int gp = px0 + pl;
    double l0 = sOut[pl][a], l1 = sOut[pl][9 + a];
    double sc = 1.0 / (1.0 + exp(l0 - l1));     // == softmax fg prob
    float scf = (float)sc;
    int gi = gp * 9 + a;
    scores[gi] = scf;
    atomicAdd(&hist[__float_as_uint(scf) >> 16], 1u);

    double dx = sOut[pl][18 + 4 * a + 0];
    double dy = sOut[pl][18 + 4 * a + 1];
    double dw = sOut[pl][18 + 4 * a + 2];
    double dh = sOut[pl][18 + 4 * a + 3];
    int wq = gp & 127, hq = gp >> 7;
    double ax1 = (double)c_anch[a][0] + 16.0 * wq;
    double ay1 = (double)c_anch[a][1] + 16.0 * hq;
    double ax2 = (double)c_anch[a][2] + 16.0 * wq;
    double ay2 = (double)c_anch[a][3] + 16.0 * hq;
    double aw = ax2 - ax1 + 1.0, ah = ay2 - ay1 + 1.0;
    double acx = ax1 + 0.5 * aw,  acy = ay1 + 0.5 * ah;
    dw = fmin(fmax(dw, -BCLIP), BCLIP);
    dh = fmin(fmax(dh, -BCLIP), BCLIP);
    double pcx = dx * aw + acx, pcy = dy * ah + acy;
    double pw = exp(dw) * aw,   ph = exp(dh) * ah;
    double x1 = fmin(fmax(pcx - 0.5 * pw, 0.0), im_w - 1.0);
    double y1 = fmin(fmax(pcy - 0.5 * ph, 0.0), im_h - 1.0);
    double x2 = fmin(fmax(pcx + 0.5 * pw, 0.0), im_w - 1.0);
    double y2 = fmin(fmax(pcy + 0.5 * ph, 0.0), im_h - 1.0);
    props[gi] = make_double4(x1, y1, x2, y2);
  }
}

// -------------------------------------------- histogram suffix scan -> cutoff
// scal[1] := smallest 16-bit bucket T such that count(key16 >= T) >= 6000.
__global__ __launch_bounds__(1024)
void scan_hist(const u32* __restrict__ hist, u32* __restrict__ scal)
{
  __shared__ u32 suf[1024];
  const int t = threadIdx.x;
  u32 s = 0;
  for (int k = 0; k < 64; ++k) s += hist[t * 64 + k];
  suf[t] = s;
  __syncthreads();
  for (int off = 1; off < 1024; off <<= 1) {
    u32 v = (t + off < 1024) ? suf[t + off] : 0u;
    __syncthreads();
    suf[t] += v;
    __syncthreads();
  }
  u32 here = suf[t];
  u32 next = (t < 1023) ? suf[t + 1] : 0u;
  if (here >= PRE_TOPN && (t == 1023 || next < PRE_TOPN)) {
    u32 cum = next;
    int T = t * 64;
    for (int b = 63; b >= 0; --b) {
      cum += hist[t * 64 + b];
      if (cum >= PRE_TOPN) { T = t * 64 + b; break; }
    }
    scal[1] = (u32)T;
  }
}

// ------------------------------------------------------------------ compact
__global__ void compact_cand(const float* __restrict__ scores,
                             u32* __restrict__ scal, u64* __restrict__ cand)
{
  int t = blockIdx.x * 256 + threadIdx.x;
  if (t >= NTOT) return;
  u32 bits = __float_as_uint(scores[t]);
  if ((bits >> 16) >= scal[1]) {
    u32 pos = atomicAdd(&scal[0], 1u);
    if (pos < CAND_CAP)
      cand[pos] = ((u64)bits << 32) | (u64)(0xFFFFFFFFu - (u32)t);
  }
}

// -------------------------- single-block bitonic sort (desc) + top-6000 gather
// key = score_bits<<32 | ~index  => descending sort == (score desc, index asc),
// exactly jax.lax.top_k tie semantics.
__global__ __launch_bounds__(1024)
void sort_topk(const u64* __restrict__ cand, const u32* __restrict__ scal,
               const double4* __restrict__ props, float* __restrict__ tscore,
               double4* __restrict__ boxes)
{
  __shared__ u64 sk[CAND_CAP];      // 128 KiB LDS
  u32 n = scal[0]; if (n > CAND_CAP) n = CAND_CAP;
  for (int t = threadIdx.x; t < CAND_CAP; t += 1024)
    sk[t] = (t < (int)n) ? cand[t] : 0ull;
  __syncthreads();
  for (int k = 2; k <= CAND_CAP; k <<= 1)
    for (int j = k >> 1; j > 0; j >>= 1) {
      for (int t = threadIdx.x; t < CAND_CAP; t += 1024) {
        int p = t ^ j;
        if (p > t) {
          u64 va = sk[t], vb = sk[p];
          bool sw = ((t & k) == 0) ? (va < vb) : (va > vb);
          if (sw) { sk[t] = vb; sk[p] = va; }
        }
      }
      __syncthreads();
    }
  for (int t = threadIdx.x; t < PRE_TOPN; t += 1024) {
    u64 key = sk[t];
    u32 idx = 0xFFFFFFFFu - (u32)key;
    tscore[t] = __uint_as_float((u32)(key >> 32));
    boxes[t]  = props[idx];
  }
}

// ------------------------------------------------------------- NMS bit mask
// mask[i][w]: bit b set iff iou(box_i, box_{64w+b}) > 0.7 and 64w+b > i.
__global__ __launch_bounds__(64)
void nms_mask(const double4* __restrict__ boxes, u64* __restrict__ mask)
{
  const int bi = blockIdx.y, bj = blockIdx.x;
  const int t = threadIdx.x;
  const int i = bi * 64 + t;
  if (bj < bi) { if (i < PRE_TOPN) mask[(u32)i * NMS_WORDS + bj] = 0ull; return; }
  __shared__ double4 cb[64];
  __shared__ double  ca[64];
  const int j0 = bj * 64;
  if (j0 + t < PRE_TOPN) {
    double4 b = boxes[j0 + t];
    cb[t] = b;
    ca[t] = (b.z - b.x + 1.0) * (b.w - b.y + 1.0);
  }
  __syncthreads();
  if (i >= PRE_TOPN) return;
  double4 bb = boxes[i];
  double ai = (bb.z - bb.x + 1.0) * (bb.w - bb.y + 1.0);
  const int jmax = min(64, PRE_TOPN - j0);
  u64 word = 0ull;
  for (int jj = 0; jj < jmax; ++jj) {
    int j = j0 + jj;
    if (j <= i) continue;
    double4 cj = cb[jj];
    double iw = fmin(bb.z, cj.z) - fmax(bb.x, cj.x) + 1.0;
    double ih = fmin(bb.w, cj.w) - fmax(bb.y, cj.y) + 1.0;
    iw = fmax(iw, 0.0); ih = fmax(ih, 0.0);
    double inter = iw * ih;
    double iou = inter / (ai + ca[jj] - inter);
    if (iou > 0.7) word |= (1ull << jj);
  }
  mask[(u32)i * NMS_WORDS + bj] = word;
}

// -------------------- serial NMS scan + top-300 select + output write (1 block)
__global__ __launch_bounds__(256)
void nms_finalize(const u64* __restrict__ mask, const double4* __restrict__ boxes,
                  const float* __restrict__ tscore, float* __restrict__ out)
{
  __shared__ u64 rem[NMS_WORDS];
  __shared__ u64 alv[NMS_WORDS];
  __shared__ int pre[NMS_WORDS + 1];
  __shared__ int keep[POST_TOPN];
  const int tid = threadIdx.x;
  if (tid < NMS_WORDS) rem[tid] = 0ull;
  __syncthreads();

  for (int c = 0; c < NMS_WORDS; ++c) {
    if (tid < 64) {
      int row = c * 64 + tid;
      u64 m = (row < PRE_TOPN) ? mask[(u32)row * NMS_WORDS + c] : 0ull;
      u64 cur = rem[c];
      for (int b = 0; b < 64; ++b) {
        u64 mb = (u64)__shfl((long long)m, b, 64);
        if (!((cur >> b) & 1ull)) cur |= mb;   // row b alive -> suppress its victims
      }
      if (tid == 0) {
        rem[c] = cur;
        u64 valid = (c == NMS_WORDS - 1) ? ((1ull << 48) - 1ull) : ~0ull;
        alv[c] = (~cur) & valid;
      }
    }
    __syncthreads();
    u64 aw = alv[c];
    for (int w = c + 1 + tid; w < NMS_WORDS; w += 256) {
      u64 acc = rem[w];
      u64 bits = aw;
      while (bits) {
        int b = __ffsll(bits) - 1;
        bits &= bits - 1;
        acc |= mask[(u32)(c * 64 + b) * NMS_WORDS + w];
      }
      rem[w] = acc;
    }
    __syncthreads();
  }

  if (tid == 0) {
    int s = 0;
    for (int c = 0; c < NMS_WORDS; ++c) { pre[c] = s; s += __popcll(alv[c]); }
    pre[NMS_WORDS] = s;
  }
  __syncthreads();
  const int total = pre[NMS_WORDS];
  if (tid < NMS_WORDS) {
    int p = pre[tid];
    u64 bits = alv[tid];
    while (bits && p < POST_TOPN) {
      int b = __ffsll(bits) - 1;
      bits &= bits - 1;
      keep[p] = tid * 64 + b;
      ++p;
    }
  }
  __syncthreads();
  if (total < POST_TOPN) {   // top_k fills with -1 (suppressed) entries, index asc
    if (tid == 0) {
      int p = total;
      for (int c = 0; c < NMS_WORDS && p < POST_TOPN; ++c) {
        u64 valid = (c == NMS_WORDS - 1) ? ((1ull << 48) - 1ull) : ~0ull;
        u64 bits = rem[c] & valid;
        while (bits && p < POST_TOPN) {
          int b = __ffsll(bits) - 1;
          bits &= bits - 1;
          keep[p++] = c * 64 + b;
        }
      }
    }
    __syncthreads();
  }

  for (int t = tid; t < POST_TOPN; t += 256) {
    int r = keep[t];
    double4 b = boxes[r];
    out[t * 5 + 0] = 0.f;
    out[t * 5 + 1] = (float)b.x;
    out[t * 5 + 2] = (float)b.y;
    out[t * 5 + 3] = (float)b.z;
    out[t * 5 + 4] = (float)b.w;
    out[POST_TOPN * 5 + t] = tscore[r];
  }
}

// --------------------------------------------------------------------- launch
extern "C" void kernel_launch(void* const* d_in, const int* in_sizes, int n_in,
                              void* d_out, int out_size, void* d_ws, size_t ws_size,
                              hipStream_t stream)
{
  const float* feature = (const float*)d_in[0];
  const int*   im_info = (const int*)d_in[1];
  const float* w_conv  = (const float*)d_in[2];
  const float* b_conv  = (const float*)d_in[3];
  const float* w_sc    = (const float*)d_in[4];
  const float* b_sc    = (const float*)d_in[5];
  const float* w_bb    = (const float*)d_in[6];
  const float* b_bb    = (const float*)d_in[7];
  float* out = (float*)d_out;

  char* ws = (char*)d_ws;
  float*   rfeat  = (float*)(ws);                 // 33,554,432 B
  float*   scores = (float*)(ws + 33554432);      //    589,824 B
  double4* props  = (double4*)(ws + 34144256);    //  4,718,592 B
  u64*     mask   = (u64*)(ws + 34144256);        // alias: used after props' last read
  u32*     hist   = (u32*)(ws + 38862848);        //    262,144 B
  u32*     scal   = (u32*)(ws + 39124992);        //        256 B  [0]=cand cnt [1]=cutoff
  u64*     cand   = (u64*)(ws + 39125248);        //    131,072 B
  float*   tscore = (float*)(ws + 39256320);      //     24,000 B
  double4* boxes  = (double4*)(ws + 39280384);    //    192,000 B  (end ~39.5 MB)

  hipMemsetAsync(hist, 0, 65536 * sizeof(u32), stream);
  hipMemsetAsync(scal, 0, 256, stream);

  conv3x3<<<512, 256, 0, stream>>>(feature, w_conv, b_conv, rfeat);
  conv1x1_decode<<<256, 256, 0, stream>>>(rfeat, w_sc, b_sc, w_bb, b_bb, im_info,
                                          scores, props, hist);
  scan_hist<<<1, 1024, 0, stream>>>(hist, scal);
  compact_cand<<<(NTOT + 255) / 256, 256, 0, stream>>>(scores, scal, cand);
  sort_topk<<<1, 1024, 0, stream>>>(cand, scal, props, tscore, boxes);
  nms_mask<<<dim3(NMS_WORDS, NMS_WORDS), 64, 0, stream>>>(boxes, mask);
  nms_finalize<<<1, 256, 0, stream>>>(mask, boxes, tscore, out);

  // third output: the feature tensor, passed through
  hipMemcpyAsync(out + POST_TOPN * 6, feature, (size_t)CC * HW * sizeof(float),
                 hipMemcpyDeviceToDevice, stream);
}

// Round 2
// 2996.200 us; speedup vs baseline: 1.2272x; 1.2272x over previous
//
#include <hip/hip_runtime.h>
#include <hip/hip_bf16.h>

// RPN proposal head for MI355X.
// conv3x3(f64 acc, conflict-free interleaved cols) -> 1x1 heads + sigmoid +
// decode (f64) -> hist -> bucket threshold -> compact -> bitonic top-6000 ->
// NMS mask -> serial-scan NMS (batched propagation) -> top-300 -> outputs.
//
// f64 on the score path: output row assignment is decided by score
// comparisons with gaps ~1e-5..1e-4; fp32 drift risks row swaps >> 40.96
// absmax threshold. fp32*fp32 is exact in double FMA.

#define HH 128
#define WW 128
#define HW 16384
#define CC 512
#define NANCH 9
#define NTOT 147456          // HW * 9
#define PRE_TOPN 6000
#define POST_TOPN 300
#define NMS_WORDS 94         // ceil(6000/64)
#define CAND_CAP 16384

typedef unsigned int u32;
typedef unsigned long long u64;

// Base anchors from _base_anchors(16): scales {8,16,32} x ratios {.5,1,2},
// numpy banker's rounding applied.
__constant__ float c_anch[9][4] = {
  { -84.f,  -40.f,  99.f,  55.f},
  {-176.f,  -88.f, 191.f, 103.f},
  {-360.f, -184.f, 375.f, 199.f},
  { -56.f,  -56.f,  71.f,  71.f},
  {-120.f, -120.f, 135.f, 135.f},
  {-248.f, -248.f, 263.f, 263.f},
  { -36.f,  -80.f,  51.f,  95.f},
  { -80.f, -168.f,  95.f, 183.f},
  {-168.f, -344.f, 183.f, 351.f}
};

// ---------------------------------------------------------------- conv 3x3
// block: 64 oc x (1 row x 128 cols), 256 threads = 16 ocg x 16 col-lanes.
// Lane p owns output cols {p, p+16, ..., p+112}: every sA read is
// lane-stride-1 (bank-conflict-free); sW reads hit 4 distinct banks.
// grid: 1024 = 8 oc-tiles (pinned to XCD via bid&7) x 128 rows.
__global__ __launch_bounds__(256, 4)
void conv3x3(const float* __restrict__ feat, const float* __restrict__ wconv,
             const float* __restrict__ bias, float* __restrict__ out)
{
  __shared__ float sA[8][3][136];   // [ic][r-1..r+1][halo(idx3) cols4..131 halo(idx132)]
  __shared__ float sW[72][64];      // [(ic*9 + ky*3 + kx)][oc]  (31.5 KB total)
  const int tid  = threadIdx.x;
  const int oc0  = (blockIdx.x & 7) << 6;   // oc tile -> fixed XCD
  const int r    = blockIdx.x >> 3;         // output row 0..127
  const int ocg  = tid >> 4;                // 0..15, 4 oc each
  const int p    = tid & 15;                // column lane

  // zero halo columns (LDS idx 3 and 132) once; staging never writes them
  if (tid < 48) {
    int ic = tid / 6, rm = tid % 6;
    sA[ic][rm >> 1][(rm & 1) ? 132 : 3] = 0.f;
  }

  double acc[4][8];
  #pragma unroll
  for (int o = 0; o < 4; ++o) {
    double bv = (double)bias[oc0 + ocg * 4 + o];
    #pragma unroll
    for (int j = 0; j < 8; ++j) acc[o][j] = bv;
  }

  for (int ic0 = 0; ic0 < CC; ic0 += 8) {
    __syncthreads();
    // stage input: 8 ic x 3 rows x 128 cols = 768 float4, coalesced
    #pragma unroll
    for (int k = 0; k < 3; ++k) {
      int s   = tid + 256 * k;        // 0..767
      int icr = s >> 5;               // 0..23
      int ic  = icr / 3, rr = icr % 3;
      int c4  = (s & 31) << 2;
      int grow = r - 1 + rr;
      float4 v = make_float4(0.f, 0.f, 0.f, 0.f);
      if (grow >= 0 && grow < HH)
        v = *reinterpret_cast<const float4*>(&feat[(ic0 + ic) * HW + grow * WW + c4]);
      *reinterpret_cast<float4*>(&sA[ic][rr][4 + c4]) = v;
    }
    // stage weights transposed: sW[tap][oc]
    {
      int oc = tid & 63, part = tid >> 6;
      const float* wp = &wconv[(size_t)((oc0 + oc) * CC + ic0) * 9 + part * 18];
      #pragma unroll
      for (int k = 0; k < 18; ++k) sW[part * 18 + k][oc] = wp[k];
    }
    __syncthreads();

    for (int ic = 0; ic < 8; ++ic) {
      #pragma unroll
      for (int ky = 0; ky < 3; ++ky) {
        double w[3][4];
        #pragma unroll
        for (int kx = 0; kx < 3; ++kx)
          #pragma unroll
          for (int o = 0; o < 4; ++o)
            w[kx][o] = (double)sW[ic * 9 + ky * 3 + kx][ocg * 4 + o];
        const float* arow = &sA[ic][ky][4];
        #pragma unroll
        for (int j = 0; j < 8; ++j) {
          int c = p + 16 * j;
          double a0 = (double)arow[c - 1];
          double a1 = (double)arow[c];
          double a2 = (double)arow[c + 1];
          #pragma unroll
          for (int o = 0; o < 4; ++o) {
            acc[o][j] = fma(a0, w[0][o], acc[o][j]);
            acc[o][j] = fma(a1, w[1][o], acc[o][j]);
            acc[o][j] = fma(a2, w[2][o], acc[o][j]);
          }
        }
      }
    }
  }

  #pragma unroll
  for (int o = 0; o < 4; ++o) {
    float* op = &out[(size_t)(oc0 + ocg * 4 + o) * HW + r * WW];
    #pragma unroll
    for (int j = 0; j < 8; ++j)
      op[p + 16 * j] = (float)acc[o][j];
  }
}

// ------------------------------------------- 1x1 heads + sigmoid + decode
__global__ __launch_bounds__(256, 2)
void conv1x1_decode(const float* __restrict__ rfeat, const float* __restrict__ wsc,
                    const float* __restrict__ bsc, const float* __restrict__ wbb,
                    const float* __restrict__ bbb, const int* __restrict__ im_info,
                    float* __restrict__ scores, double4* __restrict__ props,
                    u32* __restrict__ hist)
{
  __shared__ float  sA[32][64];
  __shared__ float  sW[32][56];
  __shared__ double sOut[64][56];
  const int tid  = threadIdx.x;
  const int px0  = blockIdx.x * 64;
  const int q    = tid >> 6;        // 0..3 -> 14 outputs each
  const int px_l = tid & 63;
  const int o0   = q * 14;

  double acc[14];
  #pragma unroll
  for (int o = 0; o < 14; ++o) {
    int oo = o0 + o;
    float b = 0.f;
    if (oo < 18) b = bsc[oo];
    else if (oo < 54) b = bbb[oo - 18];
    acc[o] = (double)b;
  }

  for (int ic0 = 0; ic0 < CC; ic0 += 32) {
    __syncthreads();
    #pragma unroll
    for (int k = 0; k < 2; ++k) {
      int s  = tid + 256 * k;
      int ic = s >> 4;
      int c4 = (s & 15) << 2;
      *reinterpret_cast<float4*>(&sA[ic][c4]) =
        *reinterpret_cast<const float4*>(&rfeat[(ic0 + ic) * HW + px0 + c4]);
    }
    for (int idx = tid; idx < 32 * 56; idx += 256) {
      int ic = idx / 56, o = idx % 56;
      float v = 0.f;
      if (o < 18) v = wsc[o * CC + ic0 + ic];
      else if (o < 54) v = wbb[(o - 18) * CC + ic0 + ic];
      sW[ic][o] = v;
    }
    __syncthreads();
    for (int ic = 0; ic < 32; ++ic) {
      double a = (double)sA[ic][px_l];
      #pragma unroll
      for (int o = 0; o < 14; ++o)
        acc[o] = fma(a, (double)sW[ic][o0 + o], acc[o]);
    }
  }
  #pragma unroll
  for (int o = 0; o < 14; ++o) sOut[px_l][o0 + o] = acc[o];
  __syncthreads();

  const double im_h = (double)im_info[0];
  const double im_w = (double)im_info[1];
  const double BCLIP = 4.1351665567423557;   // log(1000/16)
  for (int t = tid; t < 64 * NANCH; t += 256) {
    int pl = t / 9, a = t % 9;
    int gp = px0 + pl;
    double l0 = sOut[pl][a], l1 = sOut[pl][9 + a];
    double sc = 1.0 / (1.0 + exp(l0 - l1));
    float scf = (float)sc;
    int gi = gp * 9 + a;
    scores[gi] = scf;
    atomicAdd(&hist[__float_as_uint(scf) >> 16], 1u);

    double dx = sOut[pl][18 + 4 * a + 0];
    double dy = sOut[pl][18 + 4 * a + 1];
    double dw = sOut[pl][18 + 4 * a + 2];
    double dh = sOut[pl][18 + 4 * a + 3];
    int wq = gp & 127, hq = gp >> 7;
    double ax1 = (double)c_anch[a][0] + 16.0 * wq;
    double ay1 = (double)c_anch[a][1] + 16.0 * hq;
    double ax2 = (double)c_anch[a][2] + 16.0 * wq;
    double ay2 = (double)c_anch[a][3] + 16.0 * hq;
    double aw = ax2 - ax1 + 1.0, ah = ay2 - ay1 + 1.0;
    double acx = ax1 + 0.5 * aw,  acy = ay1 + 0.5 * ah;
    dw = fmin(fmax(dw, -BCLIP), BCLIP);
    dh = fmin(fmax(dh, -BCLIP), BCLIP);
    double pcx = dx * aw + acx, pcy = dy * ah + acy;
    double pw = exp(dw) * aw,   ph = exp(dh) * ah;
    double x1 = fmin(fmax(pcx - 0.5 * pw, 0.0), im_w - 1.0);
    double y1 = fmin(fmax(pcy - 0.5 * ph, 0.0), im_h - 1.0);
    double x2 = fmin(fmax(pcx + 0.5 * pw, 0.0), im_w - 1.0);
    double y2 = fmin(fmax(pcy + 0.5 * ph, 0.0), im_h - 1.0);
    props[gi] = make_double4(x1, y1, x2, y2);
  }
}

// -------------------------------------------- histogram suffix scan -> cutoff
__global__ __launch_bounds__(1024)
void scan_hist(const u32* __restrict__ hist, u32* __restrict__ scal)
{
  __shared__ u32 suf[1024];
  const int t = threadIdx.x;
  u32 s = 0;
  for (int k = 0; k < 64; ++k) s += hist[t * 64 + k];
  suf[t] = s;
  __syncthreads();
  for (int off = 1; off < 1024; off <<= 1) {
    u32 v = (t + off < 1024) ? suf[t + off] : 0u;
    __syncthreads();
    suf[t] += v;
    __syncthreads();
  }
  u32 here = suf[t];
  u32 next = (t < 1023) ? suf[t + 1] : 0u;
  if (here >= PRE_TOPN && (t == 1023 || next < PRE_TOPN)) {
    u32 cum = next;
    int T = t * 64;
    for (int b = 63; b >= 0; --b) {
      cum += hist[t * 64 + b];
      if (cum >= PRE_TOPN) { T = t * 64 + b; break; }
    }
    scal[1] = (u32)T;
  }
}

// ------------------------------------------------------------------ compact
__global__ void compact_cand(const float* __restrict__ scores,
                             u32* __restrict__ scal, u64* __restrict__ cand)
{
  int t = blockIdx.x * 256 + threadIdx.x;
  if (t >= NTOT) return;
  u32 bits = __float_as_uint(scores[t]);
  if ((bits >> 16) >= scal[1]) {
    u32 pos = atomicAdd(&scal[0], 1u);
    if (pos < CAND_CAP)
      cand[pos] = ((u64)bits << 32) | (u64)(0xFFFFFFFFu - (u32)t);
  }
}

// -------------------------- single-block bitonic sort (desc) + top-6000 gather
// key = score_bits<<32 | ~index => desc sort == (score desc, index asc) ==
// jax.lax.top_k tie semantics. Sort size 8192 when candidates fit (usual).
__global__ __launch_bounds__(1024)
void sort_topk(const u64* __restrict__ cand, const u32* __restrict__ scal,
               const double4* __restrict__ props, float* __restrict__ tscore,
               double4* __restrict__ boxes)
{
  __shared__ u64 sk[CAND_CAP];      // 128 KiB LDS
  u32 n = scal[0]; if (n > CAND_CAP) n = CAND_CAP;
  const int SZ = (n <= 8192) ? 8192 : CAND_CAP;
  for (int t = threadIdx.x; t < SZ; t += 1024)
    sk[t] = (t < (int)n) ? cand[t] : 0ull;
  __syncthreads();
  for (int k = 2; k <= SZ; k <<= 1)
    for (int j = k >> 1; j > 0; j >>= 1) {
      for (int t = threadIdx.x; t < SZ; t += 1024) {
        int p = t ^ j;
        if (p > t) {
          u64 va = sk[t], vb = sk[p];
          bool sw = ((t & k) == 0) ? (va < vb) : (va > vb);
          if (sw) { sk[t] = vb; sk[p] = va; }
        }
      }
      __syncthreads();
    }
  for (int t = threadIdx.x; t < PRE_TOPN; t += 1024) {
    u64 key = sk[t];
    u32 idx = 0xFFFFFFFFu - (u32)key;
    tscore[t] = __uint_as_float((u32)(key >> 32));
    boxes[t]  = props[idx];
  }
}

// ------------------------------------------------------------- NMS bit mask
__global__ __launch_bounds__(64)
void nms_mask(const double4* __restrict__ boxes, u64* __restrict__ mask)
{
  const int bi = blockIdx.y, bj = blockIdx.x;
  const int t = threadIdx.x;
  const int i = bi * 64 + t;
  if (bj < bi) { if (i < PRE_TOPN) mask[(u32)i * NMS_WORDS + bj] = 0ull; return; }
  __shared__ double4 cb[64];
  __shared__ double  ca[64];
  const int j0 = bj * 64;
  if (j0 + t < PRE_TOPN) {
    double4 b = boxes[j0 + t];
    cb[t] = b;
    ca[t] = (b.z - b.x + 1.0) * (b.w - b.y + 1.0);
  }
  __syncthreads();
  if (i >= PRE_TOPN) return;
  double4 bb = boxes[i];
  double ai = (bb.z - bb.x + 1.0) * (bb.w - bb.y + 1.0);
  const int jmax = min(64, PRE_TOPN - j0);
  u64 word = 0ull;
  for (int jj = 0; jj < jmax; ++jj) {
    int j = j0 + jj;
    if (j <= i) continue;
    double4 cj = cb[jj];
    double iw = fmin(bb.z, cj.z) - fmax(bb.x, cj.x) + 1.0;
    double ih = fmin(bb.w, cj.w) - fmax(bb.y, cj.y) + 1.0;
    iw = fmax(iw, 0.0); ih = fmax(ih, 0.0);
    double inter = iw * ih;
    double iou = inter / (ai + ca[jj] - inter);
    if (iou > 0.7) word |= (1ull << jj);
  }
  mask[(u32)i * NMS_WORDS + bj] = word;
}

// -------------------- serial NMS scan + top-300 select + output write (1 block)
// Propagation batches mask-row loads: alive rows gathered to a shared list,
// 2 slices per word x 4-unrolled loads (4 loads in flight vs 1 dependent).
__global__ __launch_bounds__(256)
void nms_finalize(const u64* __restrict__ mask, const double4* __restrict__ boxes,
                  const float* __restrict__ tscore, float* __restrict__ out)
{
  __shared__ u64 rem[NMS_WORDS];
  __shared__ u64 alv[NMS_WORDS];
  __shared__ int rows[68];
  __shared__ int nrows;
  __shared__ int pre[NMS_WORDS + 1];
  __shared__ int keep[POST_TOPN];
  const int tid = threadIdx.x;
  if (tid < NMS_WORDS) rem[tid] = 0ull;
  __syncthreads();

  for (int c = 0; c < NMS_WORDS; ++c) {
    // resolve chunk c on wave 0 (serial in-chunk dependency)
    if (tid < 64) {
      int row = c * 64 + tid;
      u64 m = (row < PRE_TOPN) ? mask[(u32)row * NMS_WORDS + c] : 0ull;
      u64 cur = rem[c];
      for (int b = 0; b < 64; ++b) {
        u64 mb = (u64)__shfl((long long)m, b, 64);
        if (!((cur >> b) & 1ull)) cur |= mb;
      }
      if (tid == 0) {
        rem[c] = cur;
        u64 valid = (c == NMS_WORDS - 1) ? ((1ull << 48) - 1ull) : ~0ull;
        alv[c] = (~cur) & valid;
      }
    }
    if (tid == 255) nrows = 0;
    __syncthreads();
    // gather alive rows of chunk c (order irrelevant: OR is commutative)
    if (tid < 64 && ((alv[c] >> tid) & 1ull))
      rows[atomicAdd(&nrows, 1)] = c * 64 + tid;
    __syncthreads();
    const int nr = nrows;
    if (tid < 4 && nr > 0) rows[nr + tid] = rows[0];   // pad for 4-unroll
    __syncthreads();
    // propagate: thread -> (word, slice); 4 loads in flight per group
    if (nr > 0) {
      int w = c + 1 + (tid >> 1);
      if (w < NMS_WORDS) {
        const int sl = tid & 1;
        const int G = (nr + 3) >> 2;
        u64 acc = 0ull;
        for (int g = sl; g < G; g += 2) {
          int b = g << 2;
          int r0 = rows[b], r1 = rows[b + 1], r2 = rows[b + 2], r3 = rows[b + 3];
          acc |= mask[(u32)r0 * NMS_WORDS + w] | mask[(u32)r1 * NMS_WORDS + w]
               | mask[(u32)r2 * NMS_WORDS + w] | mask[(u32)r3 * NMS_WORDS + w];
        }
        if (acc) atomicOr((unsigned long long*)&rem[w], (unsigned long long)acc);
      }
    }
    __syncthreads();
  }

  if (tid == 0) {
    int s = 0;
    for (int c = 0; c < NMS_WORDS; ++c) { pre[c] = s; s += __popcll(alv[c]); }
    pre[NMS_WORDS] = s;
  }
  __syncthreads();
  const int total = pre[NMS_WORDS];
  if (tid < NMS_WORDS) {
    int p = pre[tid];
    u64 bits = alv[tid];
    while (bits && p < POST_TOPN) {
      int b = __ffsll(bits) - 1;
      bits &= bits - 1;
      keep[p] = tid * 64 + b;
      ++p;
    }
  }
  __syncthreads();
  if (total < POST_TOPN) {   // top_k fills with -1 (suppressed) entries, index asc
    if (tid == 0) {
      int p = total;
      for (int c = 0; c < NMS_WORDS && p < POST_TOPN; ++c) {
        u64 valid = (c == NMS_WORDS - 1) ? ((1ull << 48) - 1ull) : ~0ull;
        u64 bits = rem[c] & valid;
        while (bits && p < POST_TOPN) {
          int b = __ffsll(bits) - 1;
          bits &= bits - 1;
          keep[p++] = c * 64 + b;
        }
      }
    }
    __syncthreads();
  }

  for (int t = tid; t < POST_TOPN; t += 256) {
    int r = keep[t];
    double4 b = boxes[r];
    out[t * 5 + 0] = 0.f;
    out[t * 5 + 1] = (float)b.x;
    out[t * 5 + 2] = (float)b.y;
    out[t * 5 + 3] = (float)b.z;
    out[t * 5 + 4] = (float)b.w;
    out[POST_TOPN * 5 + t] = tscore[r];
  }
}

// --------------------------------------------------------------------- launch
extern "C" void kernel_launch(void* const* d_in, const int* in_sizes, int n_in,
                              void* d_out, int out_size, void* d_ws, size_t ws_size,
                              hipStream_t stream)
{
  const float* feature = (const float*)d_in[0];
  const int*   im_info = (const int*)d_in[1];
  const float* w_conv  = (const float*)d_in[2];
  const float* b_conv  = (const float*)d_in[3];
  const float* w_sc    = (const float*)d_in[4];
  const float* b_sc    = (const float*)d_in[5];
  const float* w_bb    = (const float*)d_in[6];
  const float* b_bb    = (const float*)d_in[7];
  float* out = (float*)d_out;

  char* ws = (char*)d_ws;
  float*   rfeat  = (float*)(ws);                 // 33,554,432 B
  float*   scores = (float*)(ws + 33554432);      //    589,824 B
  double4* props  = (double4*)(ws + 34144256);    //  4,718,592 B
  u64*     mask   = (u64*)(ws + 34144256);        // alias: used after props' last read
  u32*     hist   = (u32*)(ws + 38862848);        //    262,144 B
  u32*     scal   = (u32*)(ws + 39124992);        //        256 B
  u64*     cand   = (u64*)(ws + 39125248);        //    131,072 B
  float*   tscore = (float*)(ws + 39256320);      //     24,000 B
  double4* boxes  = (double4*)(ws + 39280384);    //    192,000 B

  hipMemsetAsync(hist, 0, 65536 * sizeof(u32), stream);
  hipMemsetAsync(scal, 0, 256, stream);

  conv3x3<<<1024, 256, 0, stream>>>(feature, w_conv, b_conv, rfeat);
  conv1x1_decode<<<256, 256, 0, stream>>>(rfeat, w_sc, b_sc, w_bb, b_bb, im_info,
                                          scores, props, hist);
  scan_hist<<<1, 1024, 0, stream>>>(hist, scal);
  compact_cand<<<(NTOT + 255) / 256, 256, 0, stream>>>(scores, scal, cand);
  sort_topk<<<1, 1024, 0, stream>>>(cand, scal, props, tscore, boxes);
  nms_mask<<<dim3(NMS_WORDS, NMS_WORDS), 64, 0, stream>>>(boxes, mask);
  nms_finalize<<<1, 256, 0, stream>>>(mask, boxes, tscore, out);

  hipMemcpyAsync(out + POST_TOPN * 6, feature, (size_t)CC * HW * sizeof(float),
                 hipMemcpyDeviceToDevice, stream);
}